// Round 1
// 83.427 us; speedup vs baseline: 1.1673x; 1.1673x over previous
//
#include <hip/hip_runtime.h>
#include <stdint.h>

typedef unsigned long long u64;

#define KCAND 9
#define BATCH 16
#define NPRED 30000
#define NGT   64
#define TPB   256
#define UNR   8                    // points per thread per t-iteration
#define PPT   (TPB * UNR)          // 2048 points per block per t
#define NT    15                   // ceil(30000 / 2048)
#define PSTR  (NT * PPT)           // 30720 padded points per image
#define INITKEY 0x7F800000FFFFFFFFULL
#define FINF  __uint_as_float(0x7F800000u)

__device__ __forceinline__ u64 wave_min_u64(u64 v) {
#pragma unroll
    for (int s = 1; s < 64; s <<= 1) {
        u64 o = __shfl_xor(v, s, 64);
        v = o < v ? o : v;
    }
    return v;
}

// pre-pass: compact xy into [B][PSTR] float2, padded with +inf sentinels
// (pads produce d2 = +inf -> never below threshold, no validity checks needed)
__global__ __launch_bounds__(256) void compact_xy(
    const float* __restrict__ pred, float2* __restrict__ xy)
{
    int e = blockIdx.x * 256 + threadIdx.x;       // over BATCH*PSTR (exact multiple)
    int b = e / PSTR;
    int i = e - b * PSTR;
    float2 v;
    if (i < NPRED) {
        float4 p = ((const float4*)pred)[(size_t)b * NPRED + i];
        v = make_float2(p.x, p.y);
    } else {
        v = make_float2(FINF, FINF);
    }
    xy[e] = v;
}

// PADDED=true: xy is the padded compact buffer (stride 1 float2, float4 loads).
// PADDED=false: xy is raw pred reinterpreted (stride 2 float2, validity checks).
template <bool PADDED>
__global__ __launch_bounds__(TPB, 4) void atss_kernel(
    const float2* __restrict__ xy,
    const float*  __restrict__ pred,  // [B, N, 4] cxcywh (epilogue only)
    const float*  __restrict__ gt,    // [B, G, 4] cxcywh
    float* __restrict__ out)          // [4][B*G*K] float32
{
#pragma clang fp contract(off)
    const int tid  = threadIdx.x;
    const int lane = tid & 63;
    const int wvid = tid >> 6;

    // XCD-aware swizzle: per-XCD working set = 2 images (~0.5 MB) -> L2-resident
    const int b = (blockIdx.x & 7) + 8 * (blockIdx.x >> 9);
    const int g = (blockIdx.x >> 3) & 63;
    const int w = b * NGT + g;

    const float4 gtb = ((const float4*)gt)[w];
    const float gcx = gtb.x, gcy = gtb.y;

    const int STRIDE = PADDED ? PSTR : (NPRED * 2);   // in float2 units
    const float2* xyb   = xy + (size_t)b * STRIDE;
    const float4* pred4 = (const float4*)pred + (size_t)b * NPRED;

    // ================= pass 1: per-lane running min (no cross-lane ops) ======
    float lmin = FINF;
    for (int t = 0; t < NT; ++t) {
        float d2[UNR];
        if (PADDED) {
            const float4* x4 = (const float4*)xyb;   // 2 points per float4
#pragma unroll
            for (int k = 0; k < 4; ++k) {
                float4 q = x4[t * (PPT / 2) + k * TPB + tid];
                float dx0 = __fsub_rn(gcx, q.x), dy0 = __fsub_rn(gcy, q.y);
                d2[2 * k]     = __fadd_rn(__fmul_rn(dx0, dx0), __fmul_rn(dy0, dy0));
                float dx1 = __fsub_rn(gcx, q.z), dy1 = __fsub_rn(gcy, q.w);
                d2[2 * k + 1] = __fadd_rn(__fmul_rn(dx1, dx1), __fmul_rn(dy1, dy1));
            }
        } else {
#pragma unroll
            for (int j = 0; j < UNR; ++j) {
                const int i = t * PPT + j * TPB + tid;
                const bool v = i < NPRED;
                float2 p = xyb[(v ? i : 0) * 2];
                float dx = __fsub_rn(gcx, p.x), dy = __fsub_rn(gcy, p.y);
                float d = __fadd_rn(__fmul_rn(dx, dx), __fmul_rn(dy, dy));
                d2[j] = v ? d : FINF;
            }
        }
        float m0 = fminf(d2[0], d2[1]), m1 = fminf(d2[2], d2[3]);
        float m2 = fminf(d2[4], d2[5]), m3 = fminf(d2[6], d2[7]);
        lmin = fminf(lmin, fminf(fminf(m0, m1), fminf(m2, m3)));
    }

    // ====== threshold: T = 9th-smallest of the wave's 64 lane-mins ===========
    // Counting argument: <=8 points have d < d9, so <=8 lanes have min < d9,
    // hence the 9th order statistic of lane-mins is a guaranteed bound T >= d9.
    float vv = lmin;
    float T = FINF;
#pragma unroll
    for (int r = 0; r < KCAND; ++r) {
        float m = vv;
#pragma unroll
        for (int s = 1; s < 64; s <<= 1) m = fminf(m, __shfl_xor(m, s, 64));
        T = m;
        u64 bm = __ballot(vv == m);                 // remove ONE instance (first lane)
        if (lane == __ffsll(bm) - 1) vv = FINF;
    }

    // ================= pass 2: filtered exact top-9 (rare insertions) ========
    u64 val = INITKEY;                              // sorted top-9 in lanes 0..8
    float Tf = T;                                   // running bound, always >= d9

    for (int t = 0; t < NT; ++t) {
        float d2[UNR];
        if (PADDED) {
            const float4* x4 = (const float4*)xyb;
#pragma unroll
            for (int k = 0; k < 4; ++k) {
                float4 q = x4[t * (PPT / 2) + k * TPB + tid];
                float dx0 = __fsub_rn(gcx, q.x), dy0 = __fsub_rn(gcy, q.y);
                d2[2 * k]     = __fadd_rn(__fmul_rn(dx0, dx0), __fmul_rn(dy0, dy0));
                float dx1 = __fsub_rn(gcx, q.z), dy1 = __fsub_rn(gcy, q.w);
                d2[2 * k + 1] = __fadd_rn(__fmul_rn(dx1, dx1), __fmul_rn(dy1, dy1));
            }
        } else {
#pragma unroll
            for (int j = 0; j < UNR; ++j) {
                const int i = t * PPT + j * TPB + tid;
                const bool v = i < NPRED;
                float2 p = xyb[(v ? i : 0) * 2];
                float dx = __fsub_rn(gcx, p.x), dy = __fsub_rn(gcy, p.y);
                float d = __fadd_rn(__fmul_rn(dx, dx), __fmul_rn(dy, dy));
                d2[j] = v ? d : FINF;
            }
        }
        float m0 = fminf(d2[0], d2[1]), m1 = fminf(d2[2], d2[3]);
        float m2 = fminf(d2[4], d2[5]), m3 = fminf(d2[6], d2[7]);
        float dmin = fminf(fminf(m0, m1), fminf(m2, m3));
        if (__ballot(dmin <= Tf) == 0ULL) continue;   // ~10 candidates/wave pass

#pragma unroll
        for (int j = 0; j < UNR; ++j) {
            u64 pend = __ballot(d2[j] <= Tf);
            while (pend) {
                const int src = __ffsll(pend) - 1;
                pend &= pend - 1;
                const unsigned kd = __shfl(__float_as_uint(d2[j]), src, 64);
                unsigned ki;
                if (PADDED) {
                    const int f = t * (PPT / 2) + (j >> 1) * TPB + (tid - lane) + src;
                    ki = (unsigned)(2 * f + (j & 1));
                } else {
                    ki = (unsigned)(t * PPT + j * TPB + (tid - lane) + src);
                }
                const u64 key = ((u64)kd << 32) | ki;
                u64 Tkey = __shfl(val, 8, 64);
                if (key < Tkey) {                   // wave-uniform
                    const u64 ltm = __ballot(val < key) & 0x1FFULL;
                    const int pos = __popcll(ltm);
                    const u64 sh = __shfl_up(val, 1, 64);
                    if (lane < KCAND) {
                        if (lane == pos)      val = key;
                        else if (lane > pos)  val = sh;
                    }
                    Tkey = __shfl(val, 8, 64);
                    Tf = fminf(T, __uint_as_float((unsigned)(Tkey >> 32)));
                    pend &= __ballot(d2[j] <= Tf);  // re-prune
                }
            }
        }
    }

    // ---- cross-wave merge through LDS ----
    __shared__ u64 smem[4 * KCAND];
    if (lane < KCAND) smem[wvid * KCAND + lane] = val;
    __syncthreads();

    if (wvid != 0) return;

    u64 key = (lane < 4 * KCAND) ? smem[lane] : ~0ULL;
    u64 fin = 0;
#pragma unroll
    for (int k = 0; k < KCAND; ++k) {
        u64 m = wave_min_u64(key);
        if (lane == k) fin = m;
        if (key == m) key = ~0ULL;   // keys unique (distinct idx)
    }

    // ---- lanes 0..8: IoU + adaptive threshold + outputs ----
    const bool active = (lane < KCAND);
    const unsigned idx = active ? (unsigned)(fin & 0xffffffffu) : 0u;

    float4 pb = pred4[idx];

    float gx1 = gcx - 0.5f * gtb.z, gy1 = gcy - 0.5f * gtb.w;
    float gx2 = gcx + 0.5f * gtb.z, gy2 = gcy + 0.5f * gtb.w;
    float kx1 = pb.x - 0.5f * pb.z, ky1 = pb.y - 0.5f * pb.w;
    float kx2 = pb.x + 0.5f * pb.z, ky2 = pb.y + 0.5f * pb.w;

    float ltx = fmaxf(gx1, kx1), lty = fmaxf(gy1, ky1);
    float rbx = fminf(gx2, kx2), rby = fminf(gy2, ky2);
    float wvd = fmaxf(rbx - ltx, 0.0f);
    float hvd = fmaxf(rby - lty, 0.0f);
    float inter  = wvd * hvd;
    float area_a = (gx2 - gx1) * (gy2 - gy1);
    float area_b = (kx2 - kx1) * (ky2 - ky1);
    float iou = inter / ((area_a + area_b) - inter);

    float v = active ? iou : 0.0f;
    float s = v;
#pragma unroll
    for (int m = 1; m < 64; m <<= 1) s += __shfl_xor(s, m, 64);
    float mean = s / 9.0f;

    float dev = active ? (iou - mean) : 0.0f;
    float ss = dev * dev;
#pragma unroll
    for (int m = 1; m < 64; m <<= 1) ss += __shfl_xor(ss, m, 64);
    float stdv = sqrtf(ss / 8.0f);    // ddof = 1
    float thr = mean + stdv;

    bool inside = (gx1 <= pb.x) && (pb.x <= gx2) &&
                  (gy1 <= pb.y) && (pb.y <= gy2);
    bool maskk = (iou >= thr) && inside;

    if (active) {
        const size_t chunk = (size_t)BATCH * NGT * KCAND;   // 9216
        const size_t o = (size_t)w * KCAND + lane;
        out[0 * chunk + o] = maskk ? (float)idx : -1.0f;    // pred_idx
        out[1 * chunk + o] = maskk ? (float)g   : -1.0f;    // gt_idx
        out[2 * chunk + o] = maskk ? 1.0f : 0.0f;           // mask
        out[3 * chunk + o] = iou;                           // ious
    }
}

extern "C" void kernel_launch(void* const* d_in, const int* in_sizes, int n_in,
                              void* d_out, int out_size, void* d_ws, size_t ws_size,
                              hipStream_t stream) {
    const float* pred = (const float*)d_in[0];   // [16, 30000, 4] f32
    const float* gtb  = (const float*)d_in[1];   // [16, 64, 4] f32
    float* out = (float*)d_out;                  // 4 * 16*64*9 = 36864 f32

    const size_t need = (size_t)BATCH * PSTR * sizeof(float2);   // ~3.93 MB
    if (ws_size >= need) {
        float2* xy = (float2*)d_ws;
        compact_xy<<<BATCH * PSTR / 256, 256, 0, stream>>>(pred, xy);
        atss_kernel<true><<<BATCH * NGT, TPB, 0, stream>>>(xy, pred, gtb, out);
    } else {
        atss_kernel<false><<<BATCH * NGT, TPB, 0, stream>>>(
            (const float2*)pred, pred, gtb, out);
    }
}